// Round 5
// baseline (122.703 us; speedup 1.0000x reference)
//
#include <hip/hip_runtime.h>

// TensorProduct: out[z, o*U+u] = sum_{p: idx_out[p]==o} coeffs[p] * x0[z, idx0[p]*U+u] * x1[z, idx1[p]*U+u]
// Z=16384, U=128, NSEG=(32,8,32), P=128, all f32.
// Round 4 (118 us) was stage-latency bound: stage 40KB -> barrier(vmcnt0) -> compute,
// 3 blocks/CU couldn't cover the stage phase. Round 5: persistent blocks (2/CU, 16
// tiles each) + double-buffered LDS (2x40KB): prefetch tile i+1 during compute of
// tile i; one barrier per tile finds vmcnt already drained. + nontemporal out stores.

#define Z_DIM 16384
#define U_DIM 128
#define NSEG0 32
#define NSEG1 8
#define NSEG2 32
#define P_DIM 128
#define ZPB   2
#define BLK   512
#define NBLOCKS 512
#define NTILES  (Z_DIM / ZPB)              // 8192
#define TILES_PER_BLOCK (NTILES / NBLOCKS) // 16

#define X0_FLOATS (ZPB * NSEG0 * U_DIM)    // 8192 floats (32 KB)
#define X1_FLOATS (ZPB * NSEG1 * U_DIM)    // 2048 floats (8 KB)
#define BUF_FLOATS (X0_FLOATS + X1_FLOATS) // 10240 floats (40 KB)

typedef float f32x4 __attribute__((ext_vector_type(4)));

// ---------- setup: group the P terms by output segment, publish to ws ----------
__global__ __launch_bounds__(128) void tp_setup(
    const float* __restrict__ coeffs,
    const int* __restrict__ idx0,
    const int* __restrict__ idx1,
    const int* __restrict__ idx_out,
    int* __restrict__ off_g,     // [NSEG2+1]
    int2* __restrict__ meta_g)   // [P_DIM]: (byteoff0 | byteoff1<<16, coeff bits)
{
    __shared__ int s_cnt[NSEG2];
    __shared__ int s_off[NSEG2 + 1];
    const int t = threadIdx.x;   // exactly P_DIM threads
    if (t < NSEG2) s_cnt[t] = 0;
    __syncthreads();
    const int o = idx_out[t];
    const int r = atomicAdd(&s_cnt[o], 1);
    __syncthreads();
    if (t == 0) {
        int sum = 0;
        for (int i = 0; i < NSEG2; ++i) { s_off[i] = sum; sum += s_cnt[i]; }
        s_off[NSEG2] = sum;
    }
    __syncthreads();
    // byte offsets within a z-slice: i0*U*4 <= 15872, i1*U*4 <= 3584 (both fit 16b)
    meta_g[s_off[o] + r] = make_int2((idx0[t] * (U_DIM * 4)) | ((idx1[t] * (U_DIM * 4)) << 16),
                                     __float_as_int(coeffs[t]));
    if (t <= NSEG2) off_g[t] = s_off[t];
}

// ---------- main ----------
__device__ __forceinline__ void stage_tile(const float* __restrict__ x0,
                                           const float* __restrict__ x1,
                                           float* lbuf, size_t z0, int t)
{
    const float4* g0 = reinterpret_cast<const float4*>(x0 + z0 * (NSEG0 * U_DIM));
    const float4* g1 = reinterpret_cast<const float4*>(x1 + z0 * (NSEG1 * U_DIM));
    float4* l0 = reinterpret_cast<float4*>(lbuf);
    float4* l1 = reinterpret_cast<float4*>(lbuf + X0_FLOATS);
    #pragma unroll
    for (int i = 0; i < (X0_FLOATS / 4) / BLK; ++i)   // 4 iters
        __builtin_amdgcn_global_load_lds(
            (const __attribute__((address_space(1))) void*)(g0 + i * BLK + t),
            (__attribute__((address_space(3))) void*)(l0 + i * BLK + t),
            16, 0, 0);
    __builtin_amdgcn_global_load_lds(
        (const __attribute__((address_space(1))) void*)(g1 + t),
        (__attribute__((address_space(3))) void*)(l1 + t),
        16, 0, 0);
}

__global__ __launch_bounds__(BLK) void tp_kernel(
    const float* __restrict__ x0,
    const float* __restrict__ x1,
    const int* __restrict__ off_g,
    const int2* __restrict__ meta_g,
    float* __restrict__ out)
{
    __shared__ float buf[2][BUF_FLOATS];   // 2 x 40 KB = 80 KB -> 2 blocks/CU

    const int t  = threadIdx.x;
    const int w4 = __builtin_amdgcn_readfirstlane(t >> 6) * 4;  // SGPR segment base
    const int zl = (t >> 5) & 1;
    const int uq = t & 31;

    const size_t tile0 = (size_t)blockIdx.x * TILES_PER_BLOCK;

    // prologue: stage first tile into buf[0]
    stage_tile(x0, x1, &buf[0][0], tile0 * ZPB, t);

    int cur = 0;
    for (int i = 0; i < TILES_PER_BLOCK; ++i) {
        __syncthreads();   // stage(tile i) complete; prev tile's reads drained

        if (i + 1 < TILES_PER_BLOCK)
            stage_tile(x0, x1, &buf[cur ^ 1][0], (tile0 + i + 1) * ZPB, t);

        // --- compute tile i from buf[cur] ---
        const float* x0base = &buf[cur][zl * (NSEG0 * U_DIM) + uq * 4];
        const float* x1base = &buf[cur][X0_FLOATS + zl * (NSEG1 * U_DIM) + uq * 4];
        const size_t z = (tile0 + i) * ZPB + zl;
        float* orow = out + z * (NSEG2 * U_DIM) + uq * 4;

        #pragma unroll
        for (int oo = 0; oo < 4; ++oo) {
            const int o = w4 + oo;
            const int b = off_g[o];          // uniform -> s_load
            const int e = off_g[o + 1];
            f32x4 acc = (f32x4)0.f;
            for (int k = b; k < e; ++k) {
                const int2  m = meta_g[k];   // uniform -> s_load_dwordx2
                const float c = __int_as_float(m.y);
                const f32x4 a = *reinterpret_cast<const f32x4*>(
                    reinterpret_cast<const char*>(x0base) + (m.x & 0xffff));
                const f32x4 v = *reinterpret_cast<const f32x4*>(
                    reinterpret_cast<const char*>(x1base) + ((unsigned)m.x >> 16));
                acc += a * v * c;            // contracts to v_fma
            }
            __builtin_nontemporal_store(acc, reinterpret_cast<f32x4*>(orow + o * U_DIM));
        }
        cur ^= 1;
    }
}

extern "C" void kernel_launch(void* const* d_in, const int* in_sizes, int n_in,
                              void* d_out, int out_size, void* d_ws, size_t ws_size,
                              hipStream_t stream) {
    const float* x0      = (const float*)d_in[0];
    const float* x1      = (const float*)d_in[1];
    const float* coeffs  = (const float*)d_in[2];
    const int*   idx0    = (const int*)d_in[3];
    const int*   idx1    = (const int*)d_in[4];
    const int*   idx_out = (const int*)d_in[5];
    float* out = (float*)d_out;

    int*  off_g  = (int*)d_ws;                    // 33 ints
    int2* meta_g = (int2*)((char*)d_ws + 256);    // 128 int2

    tp_setup<<<1, P_DIM, 0, stream>>>(coeffs, idx0, idx1, idx_out, off_g, meta_g);
    tp_kernel<<<NBLOCKS, BLK, 0, stream>>>(x0, x1, off_g, meta_g, out);
}

// Round 6
// 111.088 us; speedup vs baseline: 1.1046x; 1.1046x over previous
//
#include <hip/hip_runtime.h>

// TensorProduct: out[z, o*U+u] = sum_{p: idx_out[p]==o} coeffs[p] * x0[z, idx0[p]*U+u] * x1[z, idx1[p]*U+u]
// Z=16384, U=128, NSEG=(32,8,32), P=128, all f32.
// Round 5 lesson: s_load meta + ds_read x share lgkmcnt -> forced lgkmcnt(0)
// serialization (~200cyc/term), VALUBusy 9%. Round 6: pure-DS inner loop (meta in
// LDS, staged via global_load_lds from the setup-kernel blob), 1-deep meta prefetch,
// readfirstlane scalar bounds, one-shot blocks, BLK=1024 -> 32 waves/CU.

#define Z_DIM 16384
#define U_DIM 128
#define NSEG0 32
#define NSEG1 8
#define NSEG2 32
#define P_DIM 128
#define ZPB   2
#define BLK   1024

#define X0_FLOATS (ZPB * NSEG0 * U_DIM)   // 8192 floats (32 KB)
#define X1_FLOATS (ZPB * NSEG1 * U_DIM)   // 2048 floats (8 KB)

// blob layout (ints): [0..32] seg offsets, [33..39] pad, [40..295] meta int2[128], [296..303] pad
#define META_BASE 40
#define BLOB_INTS 304                      // 1216 B = 76 * 16 B

typedef float f32x4 __attribute__((ext_vector_type(4)));

// ---------- setup: group the P terms by output segment into the ws blob ----------
__global__ __launch_bounds__(128) void tp_setup(
    const float* __restrict__ coeffs,
    const int* __restrict__ idx0,
    const int* __restrict__ idx1,
    const int* __restrict__ idx_out,
    int* __restrict__ blob)
{
    __shared__ int s_cnt[NSEG2];
    __shared__ int s_off[NSEG2 + 1];
    const int t = threadIdx.x;            // exactly P_DIM threads
    if (t < NSEG2) s_cnt[t] = 0;
    __syncthreads();
    const int o = idx_out[t];
    const int r = atomicAdd(&s_cnt[o], 1);
    __syncthreads();
    if (t == 0) {
        int sum = 0;
        for (int i = 0; i < NSEG2; ++i) { s_off[i] = sum; sum += s_cnt[i]; }
        s_off[NSEG2] = sum;
    }
    __syncthreads();
    // byte offsets within a z-slice: i0*512 <= 15872, i1*512 <= 3584 (fit 16b each)
    const int d = s_off[o] + r;
    int2* meta = reinterpret_cast<int2*>(blob + META_BASE);
    meta[d] = make_int2((idx0[t] * (U_DIM * 4)) | ((idx1[t] * (U_DIM * 4)) << 16),
                        __float_as_int(coeffs[t]));
    if (t <= NSEG2) blob[t] = s_off[t];
    if (t >= 33 && t < META_BASE) blob[t] = 0;          // pad
    if (t >= P_DIM - 8) blob[BLOB_INTS - (P_DIM - t) * 1 - 0] = 0; // tail pad [296..303]
}

// ---------- main ----------
__global__ __launch_bounds__(BLK, 8) void tp_kernel(
    const float* __restrict__ x0,
    const float* __restrict__ x1,
    const int* __restrict__ blob_g,
    float* __restrict__ out)
{
    __shared__ float s_x0[X0_FLOATS];     // 32 KB
    __shared__ float s_x1[X1_FLOATS];     //  8 KB
    __shared__ int   s_blob[BLOB_INTS];   // ~1.2 KB

    const int t = threadIdx.x;
    const size_t z0 = (size_t)blockIdx.x * ZPB;

    // --- stage x0/x1 rows + blob: async global->LDS, linear, 16 B/lane ---
    {
        const float4* g0 = reinterpret_cast<const float4*>(x0 + z0 * (NSEG0 * U_DIM));
        const float4* g1 = reinterpret_cast<const float4*>(x1 + z0 * (NSEG1 * U_DIM));
        const float4* gb = reinterpret_cast<const float4*>(blob_g);
        float4* l0 = reinterpret_cast<float4*>(s_x0);
        float4* l1 = reinterpret_cast<float4*>(s_x1);
        float4* lb = reinterpret_cast<float4*>(s_blob);
        #pragma unroll
        for (int i = 0; i < (X0_FLOATS / 4) / BLK; ++i)   // 2 iters
            __builtin_amdgcn_global_load_lds(
                (const __attribute__((address_space(1))) void*)(g0 + i * BLK + t),
                (__attribute__((address_space(3))) void*)(l0 + i * BLK + t),
                16, 0, 0);
        if (t < X1_FLOATS / 4)                             // 512 lanes
            __builtin_amdgcn_global_load_lds(
                (const __attribute__((address_space(1))) void*)(g1 + t),
                (__attribute__((address_space(3))) void*)(l1 + t),
                16, 0, 0);
        if (t < BLOB_INTS / 4)                             // 76 lanes
            __builtin_amdgcn_global_load_lds(
                (const __attribute__((address_space(1))) void*)(gb + t),
                (__attribute__((address_space(3))) void*)(lb + t),
                16, 0, 0);
    }
    __syncthreads();   // drains vmcnt; LDS tile + blob ready

    // --- compute: 16 waves x 2 segments; lanes = (zl in [0,2), uq in [0,32)) ---
    const int w  = t >> 6;
    const int zl = (t >> 5) & 1;
    const int uq = t & 31;

    const char* x0base = reinterpret_cast<const char*>(s_x0 + zl * (NSEG0 * U_DIM) + uq * 4);
    const char* x1base = reinterpret_cast<const char*>(s_x1 + zl * (NSEG1 * U_DIM) + uq * 4);
    const int2* s_meta = reinterpret_cast<const int2*>(s_blob + META_BASE);
    const size_t z = z0 + zl;
    float* orow = out + z * (NSEG2 * U_DIM) + uq * 4;

    #pragma unroll
    for (int oo = 0; oo < 2; ++oo) {
        const int o = w * 2 + oo;
        const int b = __builtin_amdgcn_readfirstlane(s_blob[o]);      // scalar bounds
        const int e = __builtin_amdgcn_readfirstlane(s_blob[o + 1]);
        f32x4 acc = (f32x4)0.f;
        int2 m = s_meta[b];                // in-bounds even when b==e==128 (pad)
        for (int k = b; k < e; ++k) {
            const int2 mn = s_meta[k + 1]; // prefetch next meta (independent addr)
            const float c = __int_as_float(m.y);
            const f32x4 a = *reinterpret_cast<const f32x4*>(x0base + (m.x & 0xffff));
            const f32x4 v = *reinterpret_cast<const f32x4*>(x1base + ((unsigned)m.x >> 16));
            acc += a * v * c;
            m = mn;
        }
        __builtin_nontemporal_store(acc, reinterpret_cast<f32x4*>(orow + o * U_DIM));
    }
}

extern "C" void kernel_launch(void* const* d_in, const int* in_sizes, int n_in,
                              void* d_out, int out_size, void* d_ws, size_t ws_size,
                              hipStream_t stream) {
    const float* x0      = (const float*)d_in[0];
    const float* x1      = (const float*)d_in[1];
    const float* coeffs  = (const float*)d_in[2];
    const int*   idx0    = (const int*)d_in[3];
    const int*   idx1    = (const int*)d_in[4];
    const int*   idx_out = (const int*)d_in[5];
    float* out = (float*)d_out;

    int* blob = (int*)d_ws;   // BLOB_INTS ints, 16B-aligned

    tp_setup<<<1, P_DIM, 0, stream>>>(coeffs, idx0, idx1, idx_out, blob);
    tp_kernel<<<Z_DIM / ZPB, BLK, 0, stream>>>(x0, x1, blob, out);
}

// Round 8
// 109.375 us; speedup vs baseline: 1.1219x; 1.0157x over previous
//
#include <hip/hip_runtime.h>

// TensorProduct: out[z, o*U+u] = sum_{p: idx_out[p]==o} coeffs[p] * x0[z, idx0[p]*U+u] * x1[z, idx1[p]*U+u]
// Z=16384, U=128, NSEG=(32,8,32), P=128, all f32. Measured HBM ~436 MB -> ~70-90 us floor.
// R6 (111 us, passed): Occ 62%, VALU 13%, HBM 33% -> stage phase unoverlapped + dispatch gaps.
// R7 (persistent dbuf + readlane meta) FAILED correctness -> shelved.
// R8 = R6 semantics, resized for TLP overlap: ZPB=1, BLK=512 -> 21.4 KB LDS ->
// 4 blocks/CU (32 waves, 100% occupancy), 16384 blocks; stage quantum halved.
// Wave = 4 segments; each 32-lane half owns 2 segments (half-divergent bounds, benign).

#define Z_DIM 16384
#define U_DIM 128
#define NSEG0 32
#define NSEG1 8
#define NSEG2 32
#define P_DIM 128
#define BLK   512

#define X0_FLOATS (NSEG0 * U_DIM)   // 4096 floats (16 KB)
#define X1_FLOATS (NSEG1 * U_DIM)   // 1024 floats (4 KB)

// blob layout (ints): [0..32] seg offsets, [33..39] pad, [40..295] meta int2[128], [296..303] pad
#define META_BASE 40
#define BLOB_INTS 304                // 1216 B = 76 * 16 B

typedef float f32x4 __attribute__((ext_vector_type(4)));

// ---------- setup: group the P terms by output segment into the ws blob ----------
__global__ __launch_bounds__(128) void tp_setup(
    const float* __restrict__ coeffs,
    const int* __restrict__ idx0,
    const int* __restrict__ idx1,
    const int* __restrict__ idx_out,
    int* __restrict__ blob)
{
    __shared__ int s_cnt[NSEG2];
    __shared__ int s_off[NSEG2 + 1];
    const int t = threadIdx.x;            // exactly P_DIM threads
    if (t < NSEG2) s_cnt[t] = 0;
    __syncthreads();
    const int o = idx_out[t];
    const int r = atomicAdd(&s_cnt[o], 1);
    __syncthreads();
    if (t == 0) {
        int sum = 0;
        for (int i = 0; i < NSEG2; ++i) { s_off[i] = sum; sum += s_cnt[i]; }
        s_off[NSEG2] = sum;
    }
    __syncthreads();
    // byte offsets within a z-slice: i0*512 <= 15872, i1*512 <= 3584 (fit 16b each)
    const int d = s_off[o] + r;
    int2* meta = reinterpret_cast<int2*>(blob + META_BASE);
    meta[d] = make_int2((idx0[t] * (U_DIM * 4)) | ((idx1[t] * (U_DIM * 4)) << 16),
                        __float_as_int(coeffs[t]));
    if (t <= NSEG2) blob[t] = s_off[t];
    if (t >= 33 && t < META_BASE) blob[t] = 0;                       // pad
    if (t >= 296 && t < BLOB_INTS) blob[t] = 0;                      // tail pad
}

// ---------- main: one z-row per block ----------
__global__ __launch_bounds__(BLK, 8) void tp_kernel(
    const float* __restrict__ x0,
    const float* __restrict__ x1,
    const int* __restrict__ blob_g,
    float* __restrict__ out)
{
    __shared__ float s_x0[X0_FLOATS];     // 16 KB
    __shared__ float s_x1[X1_FLOATS];     //  4 KB
    __shared__ int   s_blob[BLOB_INTS];   // ~1.2 KB

    const int t = threadIdx.x;
    const size_t z = (size_t)blockIdx.x;

    // --- stage x0/x1 row + blob: async global->LDS, linear, 16 B/lane ---
    {
        const float4* g0 = reinterpret_cast<const float4*>(x0 + z * (size_t)X0_FLOATS);
        const float4* g1 = reinterpret_cast<const float4*>(x1 + z * (size_t)X1_FLOATS);
        const float4* gb = reinterpret_cast<const float4*>(blob_g);
        float4* l0 = reinterpret_cast<float4*>(s_x0);
        float4* l1 = reinterpret_cast<float4*>(s_x1);
        float4* lb = reinterpret_cast<float4*>(s_blob);
        #pragma unroll
        for (int i = 0; i < (X0_FLOATS / 4) / BLK; ++i)   // 2 iters
            __builtin_amdgcn_global_load_lds(
                (const __attribute__((address_space(1))) void*)(g0 + i * BLK + t),
                (__attribute__((address_space(3))) void*)(l0 + i * BLK + t),
                16, 0, 0);
        if (t < X1_FLOATS / 4)                             // 256 lanes
            __builtin_amdgcn_global_load_lds(
                (const __attribute__((address_space(1))) void*)(g1 + t),
                (__attribute__((address_space(3))) void*)(l1 + t),
                16, 0, 0);
        if (t < BLOB_INTS / 4)                             // 76 lanes
            __builtin_amdgcn_global_load_lds(
                (const __attribute__((address_space(1))) void*)(gb + t),
                (__attribute__((address_space(3))) void*)(lb + t),
                16, 0, 0);
    }
    __syncthreads();   // drains vmcnt; LDS tile + blob ready

    // --- compute: 8 waves x 4 segments; each 32-lane half owns 2 segments ---
    const int w  = t >> 6;                // wave 0..7
    const int h  = (t >> 5) & 1;          // lane half
    const int uq = t & 31;                // float4 column

    const int seg0 = 4 * w + 2 * h;       // this half's first segment
    const char* x0base = reinterpret_cast<const char*>(s_x0 + uq * 4);
    const char* x1base = reinterpret_cast<const char*>(s_x1 + uq * 4);
    const int2* s_meta = reinterpret_cast<const int2*>(s_blob + META_BASE);
    float* orow = out + z * (NSEG2 * U_DIM) + uq * 4;

    const int b = s_blob[seg0];           // half-divergent bounds (2-valued), benign
    const int m = s_blob[seg0 + 1];
    const int e = s_blob[seg0 + 2];

    int sb = b;
    #pragma unroll
    for (int oo = 0; oo < 2; ++oo) {
        const int se = (oo == 0) ? m : e;
        f32x4 acc = (f32x4)0.f;
        int2 mt = s_meta[sb];             // s_meta[128] is pad, in-bounds
        for (int k = sb; k < se; ++k) {
            const int2 mn = s_meta[k + 1];            // depth-1 meta prefetch
            const float c = __int_as_float(mt.y);
            const f32x4 a = *reinterpret_cast<const f32x4*>(x0base + (mt.x & 0xffff));
            const f32x4 v = *reinterpret_cast<const f32x4*>(x1base + ((unsigned)mt.x >> 16));
            acc += a * v * c;             // contracts to v_fma
            mt = mn;
        }
        __builtin_nontemporal_store(acc,
            reinterpret_cast<f32x4*>(orow + (seg0 + oo) * U_DIM));
        sb = se;
    }
}

extern "C" void kernel_launch(void* const* d_in, const int* in_sizes, int n_in,
                              void* d_out, int out_size, void* d_ws, size_t ws_size,
                              hipStream_t stream) {
    const float* x0      = (const float*)d_in[0];
    const float* x1      = (const float*)d_in[1];
    const float* coeffs  = (const float*)d_in[2];
    const int*   idx0    = (const int*)d_in[3];
    const int*   idx1    = (const int*)d_in[4];
    const int*   idx_out = (const int*)d_in[5];
    float* out = (float*)d_out;

    int* blob = (int*)d_ws;   // BLOB_INTS ints, 16B-aligned

    tp_setup<<<1, P_DIM, 0, stream>>>(coeffs, idx0, idx1, idx_out, blob);
    tp_kernel<<<Z_DIM, BLK, 0, stream>>>(x0, x1, blob, out);
}